// Round 1
// baseline (103.822 us; speedup 1.0000x reference)
//
#include <hip/hip_runtime.h>
#include <hip/hip_bf16.h>
#include <math.h>

typedef __attribute__((ext_vector_type(8))) short     short8;
typedef __attribute__((ext_vector_type(8))) __bf16    bf16x8;
typedef __attribute__((ext_vector_type(4))) float     f32x4;
typedef __attribute__((ext_vector_type(2))) unsigned int u32x2;

#define NB 32
#define CI 64
#define CO 64
#define H  128
#define W  128
#define OH 126
#define OW 126
#define HW (H*W)

// LDS x-tile: 6 input rows x 66 cols x 64 ci, bf16, XOR-swizzled
#define TROWS 6
#define TCOLS 66
#define LDS_BYTES (TROWS*TCOLS*CI*2)   // 50688 B -> 2 blocks/CU

__device__ __forceinline__ unsigned int f2bf(float f) {
    // fp32 -> bf16 bits, round-to-nearest-even
    unsigned int u = __builtin_bit_cast(unsigned int, f);
    u += 0x7fffu + ((u >> 16) & 1u);
    return u >> 16;
}

// ---------------------------------------------------------------------------
// Pre-pass: weights (64,64,3,3) fp32 OIHW -> MFMA B-fragment order, bf16.
// flat elem idx = ((ks*4 + cf)*64 + lane)*8 + j
//   ks = 0..17 (khw = ks>>1, ci-half = ks&1), cf = co quarter,
//   lane: co = cf*16 + (lane&15), ci = (ks&1)*32 + 8*(lane>>4) + j
// ---------------------------------------------------------------------------
__global__ void wxform(const float* __restrict__ w, unsigned short* __restrict__ ws) {
    int tid = blockIdx.x * 256 + threadIdx.x;
    if (tid >= 18*4*64*8) return;
    int j   = tid & 7;
    int l   = (tid >> 3) & 63;
    int cf  = (tid >> 9) & 3;
    int ks  = tid >> 11;
    int co  = cf*16 + (l & 15);
    int ci  = (ks & 1)*32 + ((l >> 4) << 3) + j;
    int khw = ks >> 1;               // kh*3+kw
    int kh  = khw / 3, kw = khw % 3;
    float v = w[co*(CI*9) + ci*9 + kh*3 + kw];
    ws[tid] = (unsigned short)f2bf(v);
}

// ---------------------------------------------------------------------------
// Main: implicit-GEMM conv + channel-min + tanh(tanh()).
// Block: 4 waves; wave w owns output row (r0+w), cols c0..c0+63, all 64 co.
// B-frags VGPR-resident (3 chunks of 6 ksteps); A-frags from swizzled LDS.
// ---------------------------------------------------------------------------
__global__ __launch_bounds__(256, 2)
void conv_min_tanh(const float* __restrict__ x,
                   const unsigned short* __restrict__ wfrag,
                   const float* __restrict__ bias,
                   float* __restrict__ out) {
    __shared__ __align__(16) char xs[LDS_BYTES];

    const int lane   = threadIdx.x & 63;
    const int wv     = threadIdx.x >> 6;
    const int c0     = blockIdx.x * 64;   // ow base (0 or 64)
    const int r0     = blockIdx.y * 4;    // oh base
    const int b      = blockIdx.z;

    // ---- stage x tile (6 x 66 cols x 64 ci) as bf16 into swizzled LDS ----
    // task -> (input row r, ci block of 4); lane -> col. 96 tasks over 4 waves.
    for (int task = wv; task < 96; task += 4) {
        const int r   = task >> 4;          // 0..5
        const int ci0 = (task & 15) << 2;   // 0,4,...,60
        const int gr  = r0 + r;
        const bool rowok = (gr < H);
        const float* xp = x + ((b*CI + ci0)*H + gr)*W + c0;
        float v0=0.f, v1=0.f, v2=0.f, v3=0.f;
        if (rowok) {                         // cols c0+lane always < 128
            v0 = xp[lane]; v1 = xp[lane + HW]; v2 = xp[lane + 2*HW]; v3 = xp[lane + 3*HW];
        }
        int pix  = r*TCOLS + lane;
        int addr = (pix << 7) + (ci0 << 1);
        addr ^= (pix & 7) << 4;              // T2 swizzle
        u32x2 pk; pk.x = f2bf(v0) | (f2bf(v1) << 16); pk.y = f2bf(v2) | (f2bf(v3) << 16);
        *(u32x2*)(xs + addr) = pk;
        if (lane < 2) {                      // halo cols 64,65
            const int gc = c0 + 64 + lane;
            float t0=0.f,t1=0.f,t2=0.f,t3=0.f;
            if (rowok && gc < W) {
                const float* xq = x + ((b*CI + ci0)*H + gr)*W + gc;
                t0 = xq[0]; t1 = xq[HW]; t2 = xq[2*HW]; t3 = xq[3*HW];
            }
            pix  = r*TCOLS + 64 + lane;
            addr = (pix << 7) + (ci0 << 1);
            addr ^= (pix & 7) << 4;
            u32x2 qk; qk.x = f2bf(t0) | (f2bf(t1) << 16); qk.y = f2bf(t2) | (f2bf(t3) << 16);
            *(u32x2*)(xs + addr) = qk;
        }
    }
    __syncthreads();

    const int orow = r0 + wv;
    if (orow >= OH) return;                  // no barriers after this point

    const int lane_c = lane & 15;
    const int hi16   = (lane >> 4) << 4;     // ci-group byte offset within 128B row
    const int pbase  = wv*TCOLS + lane_c;    // pixel index base

    const short8* wp = (const short8*)wfrag;

    f32x4 acc[4][4];
    #pragma unroll
    for (int m = 0; m < 4; ++m)
        #pragma unroll
        for (int cf = 0; cf < 4; ++cf)
            acc[m][cf] = (f32x4){0.f, 0.f, 0.f, 0.f};

    #pragma unroll
    for (int ck = 0; ck < 3; ++ck) {         // 3 chunks of 6 ksteps: B stays in VGPRs
        short8 wf[6][4];
        #pragma unroll
        for (int k2 = 0; k2 < 6; ++k2)
            #pragma unroll
            for (int cf = 0; cf < 4; ++cf)
                wf[k2][cf] = wp[((ck*6 + k2)*4 + cf)*64 + lane];

        #pragma unroll
        for (int k2 = 0; k2 < 6; ++k2) {
            const int ks  = ck*6 + k2;       // compile-time after unroll
            const int khw = ks >> 1;
            const int kh  = khw / 3, kw = khw % 3;
            const int cih = ks & 1;
            #pragma unroll
            for (int m = 0; m < 4; ++m) {
                int pix  = pbase + kh*TCOLS + m*16 + kw;
                int addr = (pix << 7) + (cih << 6) + hi16;
                addr ^= (pix & 7) << 4;
                bf16x8 a = __builtin_bit_cast(bf16x8, *(const short8*)(xs + addr));
                #pragma unroll
                for (int cf = 0; cf < 4; ++cf)
                    acc[m][cf] = __builtin_amdgcn_mfma_f32_16x16x32_bf16(
                        a, __builtin_bit_cast(bf16x8, wf[k2][cf]), acc[m][cf], 0, 0, 0);
            }
        }
    }

    // ---- epilogue: +bias, min over 64 co, tanh(tanh()), store ----
    const float bs0 = bias[lane_c], bs1 = bias[16 + lane_c],
                bs2 = bias[32 + lane_c], bs3 = bias[48 + lane_c];
    float* outp = out + (b*OH + orow)*OW;
    #pragma unroll
    for (int m = 0; m < 4; ++m) {
        #pragma unroll
        for (int rg = 0; rg < 4; ++rg) {
            float v = fminf(fminf(acc[m][0][rg] + bs0, acc[m][1][rg] + bs1),
                            fminf(acc[m][2][rg] + bs2, acc[m][3][rg] + bs3));
            v = fminf(v, __shfl_xor(v, 1));
            v = fminf(v, __shfl_xor(v, 2));
            v = fminf(v, __shfl_xor(v, 4));
            v = fminf(v, __shfl_xor(v, 8));
            if (lane_c == 0) {
                const int ocol = c0 + m*16 + ((lane >> 4) << 2) + rg;
                if (ocol < OW) outp[ocol] = tanhf(tanhf(v));
            }
        }
    }
}

extern "C" void kernel_launch(void* const* d_in, const int* in_sizes, int n_in,
                              void* d_out, int out_size, void* d_ws, size_t ws_size,
                              hipStream_t stream) {
    const float* x    = (const float*)d_in[0];
    const float* w    = (const float*)d_in[1];
    const float* bias = (const float*)d_in[2];
    float* out        = (float*)d_out;
    unsigned short* wbuf = (unsigned short*)d_ws;   // needs 73728 B

    wxform<<<dim3(144), dim3(256), 0, stream>>>(w, wbuf);
    conv_min_tanh<<<dim3(2, 32, NB), dim3(256), 0, stream>>>(x, wbuf, bias, out);
}

// Round 2
// 93.902 us; speedup vs baseline: 1.1056x; 1.1056x over previous
//
#include <hip/hip_runtime.h>
#include <hip/hip_bf16.h>
#include <math.h>

typedef __attribute__((ext_vector_type(8))) short     short8;
typedef __attribute__((ext_vector_type(8))) __bf16    bf16x8;
typedef __attribute__((ext_vector_type(4))) float     f32x4;
typedef __attribute__((ext_vector_type(2))) unsigned int u32x2;

#define NB 32
#define CI 64
#define CO 64
#define H  128
#define W  128
#define OH 126
#define OW 126
#define HW (H*W)

// LDS x-tile: 6 input rows x 66 cols x 64 ci, bf16, XOR-swizzled
#define TROWS 6
#define TCOLS 66
#define LDS_BYTES (TROWS*TCOLS*CI*2)   // 50688 B -> 3 blocks/CU

__device__ __forceinline__ unsigned int f2bf(float f) {
    unsigned int u = __builtin_bit_cast(unsigned int, f);
    u += 0x7fffu + ((u >> 16) & 1u);
    return u >> 16;
}

// packed f32x2 -> bf16x2 (RNE), 1 instruction
__device__ __forceinline__ unsigned int cvt_pk_bf16(float lo, float hi) {
    unsigned int r;
    asm("v_cvt_pk_bf16_f32 %0, %1, %2" : "=v"(r) : "v"(lo), "v"(hi));
    return r;
}

// tanh(x) = 1 - 2/(exp2(2*log2e*x)+1); exact at +/-inf, ~1e-7 abs err
__device__ __forceinline__ float fast_tanh(float x) {
    float e = __builtin_amdgcn_exp2f(x * 2.8853900817779268f);
    float r = __builtin_amdgcn_rcpf(e + 1.0f);
    return 1.0f - 2.0f * r;
}

// ---------------------------------------------------------------------------
// Pre-pass: weights (64,64,3,3) fp32 OIHW -> MFMA B-fragment order, bf16.
// ---------------------------------------------------------------------------
__global__ void wxform(const float* __restrict__ w, unsigned short* __restrict__ ws) {
    int tid = blockIdx.x * 256 + threadIdx.x;
    if (tid >= 18*4*64*8) return;
    int j   = tid & 7;
    int l   = (tid >> 3) & 63;
    int cf  = (tid >> 9) & 3;
    int ks  = tid >> 11;
    int co  = cf*16 + (l & 15);
    int ci  = (ks & 1)*32 + ((l >> 4) << 3) + j;
    int khw = ks >> 1;               // kh*3+kw
    int kh  = khw / 3, kw = khw % 3;
    float v = w[co*(CI*9) + ci*9 + kh*3 + kw];
    ws[tid] = (unsigned short)f2bf(v);
}

// ---------------------------------------------------------------------------
// Main: implicit-GEMM conv + channel-min + tanh(tanh()).
// ---------------------------------------------------------------------------
__global__ __launch_bounds__(256, 3)
void conv_min_tanh(const float* __restrict__ x,
                   const unsigned short* __restrict__ wfrag,
                   const float* __restrict__ bias,
                   float* __restrict__ out) {
    __shared__ __align__(16) char xs[LDS_BYTES];

    const int lane   = threadIdx.x & 63;
    const int wv     = threadIdx.x >> 6;
    const int c0     = blockIdx.x * 64;   // ow base (0 or 64)
    const int r0     = blockIdx.y * 4;    // oh base
    const int b      = blockIdx.z;

    // ---- stage x tile (6 x 66 cols x 64 ci) as bf16 into swizzled LDS ----
    for (int task = wv; task < 96; task += 4) {
        const int r   = task >> 4;          // 0..5
        const int ci0 = (task & 15) << 2;   // 0,4,...,60
        const int gr  = r0 + r;
        const bool rowok = (gr < H);
        const float* xp = x + ((b*CI + ci0)*H + gr)*W + c0;
        float v0=0.f, v1=0.f, v2=0.f, v3=0.f;
        if (rowok) {
            v0 = xp[lane]; v1 = xp[lane + HW]; v2 = xp[lane + 2*HW]; v3 = xp[lane + 3*HW];
        }
        int pix  = r*TCOLS + lane;
        int addr = (pix << 7) + (ci0 << 1);
        addr ^= (pix & 7) << 4;              // T2 swizzle
        u32x2 pk; pk.x = cvt_pk_bf16(v0, v1); pk.y = cvt_pk_bf16(v2, v3);
        *(u32x2*)(xs + addr) = pk;
        if (lane < 2) {                      // halo cols 64,65
            const int gc = c0 + 64 + lane;
            float t0=0.f,t1=0.f,t2=0.f,t3=0.f;
            if (rowok && gc < W) {
                const float* xq = x + ((b*CI + ci0)*H + gr)*W + gc;
                t0 = xq[0]; t1 = xq[HW]; t2 = xq[2*HW]; t3 = xq[3*HW];
            }
            pix  = r*TCOLS + 64 + lane;
            addr = (pix << 7) + (ci0 << 1);
            addr ^= (pix & 7) << 4;
            u32x2 qk; qk.x = cvt_pk_bf16(t0, t1); qk.y = cvt_pk_bf16(t2, t3);
            *(u32x2*)(xs + addr) = qk;
        }
    }
    __syncthreads();

    const int orow = r0 + wv;
    if (orow >= OH) return;                  // no barriers after this point

    const int lane_c = lane & 15;
    const int hi16   = (lane >> 4) << 4;
    const int pbase  = wv*TCOLS + lane_c;

    const short8* wp = (const short8*)wfrag;

    f32x4 acc[4][4];
    #pragma unroll
    for (int m = 0; m < 4; ++m)
        #pragma unroll
        for (int cf = 0; cf < 4; ++cf)
            acc[m][cf] = (f32x4){0.f, 0.f, 0.f, 0.f};

    #pragma unroll
    for (int ck = 0; ck < 3; ++ck) {
        short8 wf[6][4];
        #pragma unroll
        for (int k2 = 0; k2 < 6; ++k2)
            #pragma unroll
            for (int cf = 0; cf < 4; ++cf)
                wf[k2][cf] = wp[((ck*6 + k2)*4 + cf)*64 + lane];

        #pragma unroll
        for (int k2 = 0; k2 < 6; ++k2) {
            const int ks  = ck*6 + k2;
            const int khw = ks >> 1;
            const int kh  = khw / 3, kw = khw % 3;
            const int cih = ks & 1;
            #pragma unroll
            for (int m = 0; m < 4; ++m) {
                int pix  = pbase + kh*TCOLS + m*16 + kw;
                int addr = (pix << 7) + (cih << 6) + hi16;
                addr ^= (pix & 7) << 4;
                bf16x8 a = __builtin_bit_cast(bf16x8, *(const short8*)(xs + addr));
                #pragma unroll
                for (int cf = 0; cf < 4; ++cf)
                    acc[m][cf] = __builtin_amdgcn_mfma_f32_16x16x32_bf16(
                        a, __builtin_bit_cast(bf16x8, wf[k2][cf]), acc[m][cf], 0, 0, 0);
            }
        }
    }

    // ---- epilogue: +bias, min over 64 co, tanh(tanh()), store ----
    const float bs0 = bias[lane_c], bs1 = bias[16 + lane_c],
                bs2 = bias[32 + lane_c], bs3 = bias[48 + lane_c];
    float* outp = out + (b*OH + orow)*OW;
    #pragma unroll
    for (int m = 0; m < 4; ++m) {
        #pragma unroll
        for (int rg = 0; rg < 4; ++rg) {
            float v = fminf(fminf(acc[m][0][rg] + bs0, acc[m][1][rg] + bs1),
                            fminf(acc[m][2][rg] + bs2, acc[m][3][rg] + bs3));
            v = fminf(v, __shfl_xor(v, 1));
            v = fminf(v, __shfl_xor(v, 2));
            v = fminf(v, __shfl_xor(v, 4));
            v = fminf(v, __shfl_xor(v, 8));
            float vt = fast_tanh(fast_tanh(v));   // unconditional: no divergent libm
            const int ocol = c0 + m*16 + ((lane >> 4) << 2) + rg;
            if (lane_c == 0 && ocol < OW) outp[ocol] = vt;
        }
    }
}

extern "C" void kernel_launch(void* const* d_in, const int* in_sizes, int n_in,
                              void* d_out, int out_size, void* d_ws, size_t ws_size,
                              hipStream_t stream) {
    const float* x    = (const float*)d_in[0];
    const float* w    = (const float*)d_in[1];
    const float* bias = (const float*)d_in[2];
    float* out        = (float*)d_out;
    unsigned short* wbuf = (unsigned short*)d_ws;   // needs 73728 B

    wxform<<<dim3(144), dim3(256), 0, stream>>>(w, wbuf);
    conv_min_tanh<<<dim3(2, 32, NB), dim3(256), 0, stream>>>(x, wbuf, bias, out);
}

// Round 3
// 69.490 us; speedup vs baseline: 1.4940x; 1.3513x over previous
//
#include <hip/hip_runtime.h>
#include <hip/hip_bf16.h>
#include <math.h>

typedef __attribute__((ext_vector_type(8))) short     short8;
typedef __attribute__((ext_vector_type(8))) __bf16    bf16x8;
typedef __attribute__((ext_vector_type(4))) float     f32x4;
typedef __attribute__((ext_vector_type(2))) unsigned int u32x2;

#define NB 32
#define CI 64
#define CO 64
#define H  128
#define W  128
#define OH 126
#define OW 126
#define HW (H*W)

// LDS x-tile: 6 input rows x 66 cols x 64 ci, bf16, XOR-swizzled
#define TROWS 6
#define TCOLS 66
#define LDS_BYTES (TROWS*TCOLS*CI*2)   // 50688 B -> 3 blocks/CU

__device__ __forceinline__ unsigned int f2bf(float f) {
    unsigned int u = __builtin_bit_cast(unsigned int, f);
    u += 0x7fffu + ((u >> 16) & 1u);
    return u >> 16;
}

// packed f32x2 -> bf16x2 (RNE), 1 instruction
__device__ __forceinline__ unsigned int cvt_pk_bf16(float lo, float hi) {
    unsigned int r;
    asm("v_cvt_pk_bf16_f32 %0, %1, %2" : "=v"(r) : "v"(lo), "v"(hi));
    return r;
}

// tanh(x) = 1 - 2/(exp2(2*log2e*x)+1); exact at +/-inf, ~1e-7 abs err
__device__ __forceinline__ float fast_tanh(float x) {
    float e = __builtin_amdgcn_exp2f(x * 2.8853900817779268f);
    float r = __builtin_amdgcn_rcpf(e + 1.0f);
    return 1.0f - 2.0f * r;
}

// ---------------------------------------------------------------------------
// Pre-pass: weights (64,64,3,3) fp32 OIHW -> MFMA B-fragment order, bf16.
// flat elem idx = ((ks*4 + cf)*64 + lane)*8 + j
//   ks = 0..17 (khw = ks>>1, ci-half = ks&1), cf = co quarter,
//   lane: co = cf*16 + (lane&15), ci = (ks&1)*32 + 8*(lane>>4) + j
// ---------------------------------------------------------------------------
__global__ void wxform(const float* __restrict__ w, unsigned short* __restrict__ ws) {
    int tid = blockIdx.x * 256 + threadIdx.x;
    if (tid >= 18*4*64*8) return;
    int j   = tid & 7;
    int l   = (tid >> 3) & 63;
    int cf  = (tid >> 9) & 3;
    int ks  = tid >> 11;
    int co  = cf*16 + (l & 15);
    int ci  = (ks & 1)*32 + ((l >> 4) << 3) + j;
    int khw = ks >> 1;               // kh*3+kw
    int kh  = khw / 3, kw = khw % 3;
    float v = w[co*(CI*9) + ci*9 + kh*3 + kw];
    ws[tid] = (unsigned short)f2bf(v);
}

// ---------------------------------------------------------------------------
// Main: implicit-GEMM conv + channel-min + tanh(tanh()).
// Block: 4 waves; wave w owns output row (r0+w), cols c0..c0+63, all 64 co.
// Staging: issue-all-loads-then-convert (latency batched). B-frags double-
// buffered in VGPRs. A-frag LDS addresses precomputed (zero VALU per read).
// ---------------------------------------------------------------------------
__global__ __launch_bounds__(256, 3)
void conv_min_tanh(const float* __restrict__ x,
                   const unsigned short* __restrict__ wfrag,
                   const float* __restrict__ bias,
                   float* __restrict__ out) {
    __shared__ __align__(16) char xs[LDS_BYTES];

    const int lane   = threadIdx.x & 63;
    const int wv     = threadIdx.x >> 6;
    const int c0     = blockIdx.x * 64;   // ow base (0 or 64)
    const int r0     = blockIdx.y * 4;    // oh base
    const int b      = blockIdx.z;

    const float* xb = x + b*CI*HW;

    // ---- Phase 1: issue ALL staging loads up front (96 in flight/wave) ----
    float v[24][4];
    #pragma unroll
    for (int i = 0; i < 24; ++i) {
        const int task = wv + 4*i;
        const int r    = task >> 4;          // 0..5
        const int ci0  = (task & 15) << 2;   // 0,4,...,60
        const int gr   = r0 + r;
        v[i][0] = 0.f; v[i][1] = 0.f; v[i][2] = 0.f; v[i][3] = 0.f;
        if (gr < H) {                         // wave-uniform branch
            const float* xp = xb + ci0*HW + gr*W + c0 + lane;
            v[i][0] = xp[0]; v[i][1] = xp[HW]; v[i][2] = xp[2*HW]; v[i][3] = xp[3*HW];
        }
    }
    // halo cols 64,65: 6 rows x 2 cols x 16 ci-quads = 192 one-shot tasks
    const int t = threadIdx.x;
    float h0=0.f, h1=0.f, h2=0.f, h3=0.f;
    int hpix = 0, hci0 = 0;
    const bool hdo = t < 192;
    if (hdo) {
        const int r   = t >> 5;              // 0..5
        const int sub = t & 31;
        const int gc  = c0 + 64 + (sub & 1);
        hci0 = (sub >> 1) << 2;              // 0..60
        const int gr  = r0 + r;
        hpix = r*TCOLS + 64 + (sub & 1);
        if (gr < H && gc < W) {
            const float* xq = xb + hci0*HW + gr*W + gc;
            h0 = xq[0]; h1 = xq[HW]; h2 = xq[2*HW]; h3 = xq[3*HW];
        }
    }

    // ---- Phase 2: convert + LDS write (waits retire in issue order) ----
    #pragma unroll
    for (int i = 0; i < 24; ++i) {
        const int task = wv + 4*i;
        const int r    = task >> 4;
        const int ci0  = (task & 15) << 2;
        int pix  = r*TCOLS + lane;
        int addr = (pix << 7) + (ci0 << 1);
        addr ^= (pix & 7) << 4;              // T2 swizzle
        u32x2 pk; pk.x = cvt_pk_bf16(v[i][0], v[i][1]); pk.y = cvt_pk_bf16(v[i][2], v[i][3]);
        *(u32x2*)(xs + addr) = pk;
    }
    if (hdo) {
        int addr = (hpix << 7) + (hci0 << 1);
        addr ^= (hpix & 7) << 4;
        u32x2 qk; qk.x = cvt_pk_bf16(h0, h1); qk.y = cvt_pk_bf16(h2, h3);
        *(u32x2*)(xs + addr) = qk;
    }

    // ---- preload B-frag chunk 0 (L2 latency hides under the barrier) ----
    const short8* wp = (const short8*)wfrag;
    short8 wf[2][2][4];                      // double buffer: 2 ksteps x 4 co-frags
    #pragma unroll
    for (int k2 = 0; k2 < 2; ++k2)
        #pragma unroll
        for (int cf = 0; cf < 4; ++cf)
            wf[0][k2][cf] = wp[(k2*4 + cf)*64 + lane];

    __syncthreads();

    const int orow = r0 + wv;
    if (orow >= OH) return;                  // no barriers after this point

    const int lane_c = lane & 15;
    const int hi16   = (lane >> 4) << 4;

    // ---- precompute 18 LDS base addrs [khw][cih]; reads use +m*2048 imm ----
    int abase[9][2];
    #pragma unroll
    for (int kh = 0; kh < 3; ++kh)
        #pragma unroll
        for (int kw = 0; kw < 3; ++kw) {
            const int pix  = (wv + kh)*TCOLS + lane_c + kw;
            const int swz  = (pix & 7) << 4;
            #pragma unroll
            for (int cih = 0; cih < 2; ++cih)
                abase[kh*3 + kw][cih] = (((pix << 7) + (cih << 6) + hi16)) ^ swz;
        }

    f32x4 acc[4][4];
    #pragma unroll
    for (int m = 0; m < 4; ++m)
        #pragma unroll
        for (int cf = 0; cf < 4; ++cf)
            acc[m][cf] = (f32x4){0.f, 0.f, 0.f, 0.f};

    // ---- main loop: 9 chunks of 2 ksteps, wf double-buffered ----
    #pragma unroll
    for (int ck = 0; ck < 9; ++ck) {
        const int buf = ck & 1;
        if (ck < 8) {                        // prefetch next chunk
            #pragma unroll
            for (int k2 = 0; k2 < 2; ++k2)
                #pragma unroll
                for (int cf = 0; cf < 4; ++cf)
                    wf[buf ^ 1][k2][cf] = wp[(((ck + 1)*2 + k2)*4 + cf)*64 + lane];
        }
        #pragma unroll
        for (int k2 = 0; k2 < 2; ++k2) {     // ks = ck*2+k2: khw = ck, cih = k2
            #pragma unroll
            for (int m = 0; m < 4; ++m) {
                const short8 av = *(const short8*)(xs + abase[ck][k2] + m*2048);
                const bf16x8 a = __builtin_bit_cast(bf16x8, av);
                #pragma unroll
                for (int cf = 0; cf < 4; ++cf)
                    acc[m][cf] = __builtin_amdgcn_mfma_f32_16x16x32_bf16(
                        a, __builtin_bit_cast(bf16x8, wf[buf][k2][cf]), acc[m][cf], 0, 0, 0);
            }
        }
    }

    // ---- epilogue: +bias, min over 64 co, tanh(tanh()), store ----
    const float bs0 = bias[lane_c], bs1 = bias[16 + lane_c],
                bs2 = bias[32 + lane_c], bs3 = bias[48 + lane_c];
    float* outp = out + (b*OH + orow)*OW;
    #pragma unroll
    for (int m = 0; m < 4; ++m) {
        #pragma unroll
        for (int rg = 0; rg < 4; ++rg) {
            float v0 = fminf(fminf(acc[m][0][rg] + bs0, acc[m][1][rg] + bs1),
                             fminf(acc[m][2][rg] + bs2, acc[m][3][rg] + bs3));
            v0 = fminf(v0, __shfl_xor(v0, 1));
            v0 = fminf(v0, __shfl_xor(v0, 2));
            v0 = fminf(v0, __shfl_xor(v0, 4));
            v0 = fminf(v0, __shfl_xor(v0, 8));
            const float vt = fast_tanh(fast_tanh(v0));
            const int ocol = c0 + m*16 + ((lane >> 4) << 2) + rg;
            if (lane_c == 0 && ocol < OW) outp[ocol] = vt;
        }
    }
}

extern "C" void kernel_launch(void* const* d_in, const int* in_sizes, int n_in,
                              void* d_out, int out_size, void* d_ws, size_t ws_size,
                              hipStream_t stream) {
    const float* x    = (const float*)d_in[0];
    const float* w    = (const float*)d_in[1];
    const float* bias = (const float*)d_in[2];
    float* out        = (float*)d_out;
    unsigned short* wbuf = (unsigned short*)d_ws;   // needs 73728 B

    wxform<<<dim3(144), dim3(256), 0, stream>>>(w, wbuf);
    conv_min_tanh<<<dim3(2, 32, NB), dim3(256), 0, stream>>>(x, wbuf, bias, out);
}

// Round 4
// 67.455 us; speedup vs baseline: 1.5391x; 1.0302x over previous
//
#include <hip/hip_runtime.h>
#include <hip/hip_bf16.h>
#include <math.h>

typedef __attribute__((ext_vector_type(8))) short     short8;
typedef __attribute__((ext_vector_type(8))) __bf16    bf16x8;
typedef __attribute__((ext_vector_type(4))) float     f32x4;
typedef __attribute__((ext_vector_type(2))) unsigned int u32x2;

#define NB 32
#define CI 64
#define CO 64
#define H  128
#define W  128
#define OH 126
#define OW 126
#define HW (H*W)

// LDS x-tile: 6 input rows x 66 cols x 64 ci, bf16, XOR-swizzled
#define TROWS 6
#define TCOLS 66
#define LDS_BYTES (TROWS*TCOLS*CI*2)   // 50688 B -> 3 blocks/CU

__device__ __forceinline__ unsigned int f2bf(float f) {
    unsigned int u = __builtin_bit_cast(unsigned int, f);
    u += 0x7fffu + ((u >> 16) & 1u);
    return u >> 16;
}

// packed f32x2 -> bf16x2 (RNE), 1 instruction
__device__ __forceinline__ unsigned int cvt_pk_bf16(float lo, float hi) {
    unsigned int r;
    asm("v_cvt_pk_bf16_f32 %0, %1, %2" : "=v"(r) : "v"(lo), "v"(hi));
    return r;
}

// tanh(x) = 1 - 2/(exp2(2*log2e*x)+1); exact at +/-inf, ~1e-7 abs err
__device__ __forceinline__ float fast_tanh(float x) {
    float e = __builtin_amdgcn_exp2f(x * 2.8853900817779268f);
    float r = __builtin_amdgcn_rcpf(e + 1.0f);
    return 1.0f - 2.0f * r;
}

// ---------------------------------------------------------------------------
// Pre-pass: weights (64,64,3,3) fp32 OIHW -> MFMA B-fragment order, bf16.
// flat elem idx = ((ks*4 + cf)*64 + lane)*8 + j
//   ks = 0..17 (khw = ks>>1, ci-half = ks&1), cf = co quarter,
//   lane: co = cf*16 + (lane&15), ci = (ks&1)*32 + 8*(lane>>4) + j
// ---------------------------------------------------------------------------
__global__ void wxform(const float* __restrict__ w, unsigned short* __restrict__ ws) {
    int tid = blockIdx.x * 256 + threadIdx.x;
    if (tid >= 18*4*64*8) return;
    int j   = tid & 7;
    int l   = (tid >> 3) & 63;
    int cf  = (tid >> 9) & 3;
    int ks  = tid >> 11;
    int co  = cf*16 + (l & 15);
    int ci  = (ks & 1)*32 + ((l >> 4) << 3) + j;
    int khw = ks >> 1;               // kh*3+kw
    int kh  = khw / 3, kw = khw % 3;
    float v = w[co*(CI*9) + ci*9 + kh*3 + kw];
    ws[tid] = (unsigned short)f2bf(v);
}

// ---------------------------------------------------------------------------
// Main: implicit-GEMM conv + channel-min + tanh(tanh()).
// Block: 4 waves; wave w owns output row (r0+w), cols c0..c0+63, all 64 co.
// Staging: ALL loads issued before ANY convert/write, pinned by
// sched_barrier(0) -> exposed latency = 1 HBM round trip, not 24.
// ---------------------------------------------------------------------------
__global__ __launch_bounds__(256, 3)
void conv_min_tanh(const float* __restrict__ x,
                   const unsigned short* __restrict__ wfrag,
                   const float* __restrict__ bias,
                   float* __restrict__ out) {
    __shared__ __align__(16) char xs[LDS_BYTES];

    const int lane   = threadIdx.x & 63;
    const int wv     = threadIdx.x >> 6;
    const int c0     = blockIdx.x * 64;   // ow base (0 or 64)
    const int r0     = blockIdx.y * 4;    // oh base
    const int b      = blockIdx.z;

    const float* xb = x + b*CI*HW;

    // ---- Phase 1: issue ALL staging loads (96 main + 4 halo per thread) ----
    float v[24][4];
    #pragma unroll
    for (int i = 0; i < 24; ++i) {
        const int task = wv + 4*i;
        const int r    = task >> 4;          // 0..5
        const int ci0  = (task & 15) << 2;   // 0,4,...,60
        const int gr   = r0 + r;
        v[i][0] = 0.f; v[i][1] = 0.f; v[i][2] = 0.f; v[i][3] = 0.f;
        if (gr < H) {                         // wave-uniform branch
            const float* xp = xb + ci0*HW + gr*W + c0 + lane;
            v[i][0] = xp[0]; v[i][1] = xp[HW]; v[i][2] = xp[2*HW]; v[i][3] = xp[3*HW];
        }
    }
    // halo cols 64,65: 6 rows x 2 cols x 16 ci-quads = 192 one-shot tasks
    const int t = threadIdx.x;
    float h0=0.f, h1=0.f, h2=0.f, h3=0.f;
    int hpix = 0, hci0 = 0;
    const bool hdo = t < 192;
    if (hdo) {
        const int r   = t >> 5;              // 0..5
        const int sub = t & 31;
        const int gc  = c0 + 64 + (sub & 1);
        hci0 = (sub >> 1) << 2;              // 0..60
        const int gr  = r0 + r;
        hpix = r*TCOLS + 64 + (sub & 1);
        if (gr < H && gc < W) {
            const float* xq = xb + hci0*HW + gr*W + gc;
            h0 = xq[0]; h1 = xq[HW]; h2 = xq[2*HW]; h3 = xq[3*HW];
        }
    }
    // ---- preload B-frag chunk 0 (latency hides under convert phase) ----
    const short8* wp = (const short8*)wfrag;
    short8 wf[2][2][4];                      // double buffer: 2 ksteps x 4 co-frags
    #pragma unroll
    for (int k2 = 0; k2 < 2; ++k2)
        #pragma unroll
        for (int cf = 0; cf < 4; ++cf)
            wf[0][k2][cf] = wp[(k2*4 + cf)*64 + lane];

    // FENCE: nothing below may be hoisted above (keeps all loads in flight)
    __builtin_amdgcn_sched_barrier(0);

    // ---- Phase 2: convert + LDS write (waits retire in issue order) ----
    #pragma unroll
    for (int i = 0; i < 24; ++i) {
        const int task = wv + 4*i;
        const int r    = task >> 4;
        const int ci0  = (task & 15) << 2;
        int pix  = r*TCOLS + lane;
        int addr = (pix << 7) + (ci0 << 1);
        addr ^= (pix & 7) << 4;              // T2 swizzle
        u32x2 pk; pk.x = cvt_pk_bf16(v[i][0], v[i][1]); pk.y = cvt_pk_bf16(v[i][2], v[i][3]);
        *(u32x2*)(xs + addr) = pk;
    }
    if (hdo) {
        int addr = (hpix << 7) + (hci0 << 1);
        addr ^= (hpix & 7) << 4;
        u32x2 qk; qk.x = cvt_pk_bf16(h0, h1); qk.y = cvt_pk_bf16(h2, h3);
        *(u32x2*)(xs + addr) = qk;
    }

    __syncthreads();

    const int orow = r0 + wv;
    if (orow >= OH) return;                  // no barriers after this point

    const int lane_c = lane & 15;
    const int hi16   = (lane >> 4) << 4;

    // ---- precompute 18 LDS base addrs [khw][cih]; reads use +m*2048 imm ----
    int abase[9][2];
    #pragma unroll
    for (int kh = 0; kh < 3; ++kh)
        #pragma unroll
        for (int kw = 0; kw < 3; ++kw) {
            const int pix  = (wv + kh)*TCOLS + lane_c + kw;
            const int swz  = (pix & 7) << 4;
            #pragma unroll
            for (int cih = 0; cih < 2; ++cih)
                abase[kh*3 + kw][cih] = (((pix << 7) + (cih << 6) + hi16)) ^ swz;
        }

    f32x4 acc[4][4];
    #pragma unroll
    for (int m = 0; m < 4; ++m)
        #pragma unroll
        for (int cf = 0; cf < 4; ++cf)
            acc[m][cf] = (f32x4){0.f, 0.f, 0.f, 0.f};

    // ---- main loop: 9 chunks of 2 ksteps, wf double-buffered ----
    #pragma unroll
    for (int ck = 0; ck < 9; ++ck) {
        const int buf = ck & 1;
        if (ck < 8) {                        // prefetch next chunk
            #pragma unroll
            for (int k2 = 0; k2 < 2; ++k2)
                #pragma unroll
                for (int cf = 0; cf < 4; ++cf)
                    wf[buf ^ 1][k2][cf] = wp[(((ck + 1)*2 + k2)*4 + cf)*64 + lane];
        }
        #pragma unroll
        for (int k2 = 0; k2 < 2; ++k2) {     // ks = ck*2+k2: khw = ck, cih = k2
            #pragma unroll
            for (int m = 0; m < 4; ++m) {
                const short8 av = *(const short8*)(xs + abase[ck][k2] + m*2048);
                const bf16x8 a = __builtin_bit_cast(bf16x8, av);
                #pragma unroll
                for (int cf = 0; cf < 4; ++cf)
                    acc[m][cf] = __builtin_amdgcn_mfma_f32_16x16x32_bf16(
                        a, __builtin_bit_cast(bf16x8, wf[buf][k2][cf]), acc[m][cf], 0, 0, 0);
            }
        }
    }

    // ---- epilogue: +bias, min over 64 co, tanh(tanh()), store ----
    const float bs0 = bias[lane_c], bs1 = bias[16 + lane_c],
                bs2 = bias[32 + lane_c], bs3 = bias[48 + lane_c];
    float* outp = out + (b*OH + orow)*OW;
    #pragma unroll
    for (int m = 0; m < 4; ++m) {
        #pragma unroll
        for (int rg = 0; rg < 4; ++rg) {
            float v0 = fminf(fminf(acc[m][0][rg] + bs0, acc[m][1][rg] + bs1),
                             fminf(acc[m][2][rg] + bs2, acc[m][3][rg] + bs3));
            v0 = fminf(v0, __shfl_xor(v0, 1));
            v0 = fminf(v0, __shfl_xor(v0, 2));
            v0 = fminf(v0, __shfl_xor(v0, 4));
            v0 = fminf(v0, __shfl_xor(v0, 8));
            const float vt = fast_tanh(fast_tanh(v0));
            const int ocol = c0 + m*16 + ((lane >> 4) << 2) + rg;
            if (lane_c == 0 && ocol < OW) outp[ocol] = vt;
        }
    }
}

extern "C" void kernel_launch(void* const* d_in, const int* in_sizes, int n_in,
                              void* d_out, int out_size, void* d_ws, size_t ws_size,
                              hipStream_t stream) {
    const float* x    = (const float*)d_in[0];
    const float* w    = (const float*)d_in[1];
    const float* bias = (const float*)d_in[2];
    float* out        = (float*)d_out;
    unsigned short* wbuf = (unsigned short*)d_ws;   // needs 73728 B

    wxform<<<dim3(144), dim3(256), 0, stream>>>(w, wbuf);
    conv_min_tanh<<<dim3(2, 32, NB), dim3(256), 0, stream>>>(x, wbuf, bias, out);
}